// Round 1
// baseline (230.290 us; speedup 1.0000x reference)
//
#include <hip/hip_runtime.h>
#include <hip/hip_bf16.h>
#include <stdint.h>

typedef __bf16 bf16;
typedef __bf16 bf16x2 __attribute__((ext_vector_type(2)));
typedef __bf16 bf16x4 __attribute__((ext_vector_type(4)));
typedef __bf16 bf16x8 __attribute__((ext_vector_type(8)));
typedef float f32x4 __attribute__((ext_vector_type(4)));

#define AS1 __attribute__((address_space(1)))
#define AS3 __attribute__((address_space(3)))

// B=4 S=2048 E=512 H=8 D=64; tokens M = 8192; all K dims = 512 or 64.

// ---------------- prep: cast x to bf16 ----------------
__global__ void cast_x_kernel(const float* __restrict__ x, bf16* __restrict__ xb) {
  int i = blockIdx.x * blockDim.x + threadIdx.x;  // over float4s, exactly 1M
  float4 v = reinterpret_cast<const float4*>(x)[i];
  bf16x4 o = { (bf16)v.x, (bf16)v.y, (bf16)v.z, (bf16)v.w };
  *reinterpret_cast<bf16x4*>(xb + (size_t)i * 4) = o;
}

// ---------------- prep: W[k][n] -> Wt[n][k] bf16 ----------------
__global__ void transpose_w_kernel(const float* __restrict__ W, bf16* __restrict__ Wt) {
  int t = blockIdx.x * blockDim.x + threadIdx.x;  // 0..262143
  int n = t >> 9, kk = t & 511;
  Wt[t] = (bf16)W[kk * 512 + n];
}

// ---------------- GEMM (TN): C[m][n] = sum_k A[m][k] * Bt[n][k] + bias[n] ----------------
// MODE 0: out = bf16, scatter to [B,H,S,D] split-head layout, scaled (for Q: 0.125)
// MODE 1: out = f32 row-major [M][512]
template<int MODE>
__global__ __launch_bounds__(256) void gemm_tn_kernel(
    const bf16* __restrict__ A, const bf16* __restrict__ Bt,
    const float* __restrict__ bias, bf16* __restrict__ out_bf,
    float* __restrict__ out_f, float scale)
{
  __shared__ bf16 As[128 * 64];
  __shared__ bf16 Bs[128 * 64];
  const int tid = threadIdx.x;
  const int lane = tid & 63;
  const int w = tid >> 6;
  const int wm = w >> 1, wn = w & 1;           // 2x2 wave grid, 64x64 per wave
  const int m0 = blockIdx.x * 128, n0 = blockIdx.y * 128;
  const int cl = lane & 15, hi = lane >> 4;

  f32x4 acc[4][4] = {};

  // staging: per wave 4 calls x 1KB (8 rows of 128B); lane l covers row (l>>3), chunk (l&7)
  const int lr = lane >> 3;
  const int cofs = ((lane & 7) << 4) ^ (lr << 4);   // pre-swizzled source byte col (T2/m173)

  const char* Abase = (const char*)A;
  const char* Bbase = (const char*)Bt;

  for (int kt = 0; kt < 512; kt += 64) {
    __syncthreads();
#pragma unroll
    for (int c = 0; c < 4; ++c) {
      int rA = m0 + w * 32 + c * 8 + lr;
      const void* srcA = Abase + ((size_t)rA * 512 + kt) * 2 + cofs;
      void* dstA = (char*)As + w * 4096 + c * 1024;
      __builtin_amdgcn_global_load_lds((const AS1 void*)srcA, (AS3 void*)dstA, 16, 0, 0);
      int rB = n0 + w * 32 + c * 8 + lr;
      const void* srcB = Bbase + ((size_t)rB * 512 + kt) * 2 + cofs;
      void* dstB = (char*)Bs + w * 4096 + c * 1024;
      __builtin_amdgcn_global_load_lds((const AS1 void*)srcB, (AS3 void*)dstB, 16, 0, 0);
    }
    __syncthreads();
#pragma unroll
    for (int ks = 0; ks < 2; ++ks) {
      bf16x8 af[4], bfv[4];
#pragma unroll
      for (int mt = 0; mt < 4; ++mt) {
        int r = wm * 64 + mt * 16 + cl;
        int cb = (ks * 64 + (hi << 4)) ^ ((r & 7) << 4);
        af[mt] = *(const bf16x8*)((const char*)As + r * 128 + cb);
      }
#pragma unroll
      for (int nt = 0; nt < 4; ++nt) {
        int r = wn * 64 + nt * 16 + cl;
        int cb = (ks * 64 + (hi << 4)) ^ ((r & 7) << 4);
        bfv[nt] = *(const bf16x8*)((const char*)Bs + r * 128 + cb);
      }
#pragma unroll
      for (int mt = 0; mt < 4; ++mt)
#pragma unroll
        for (int nt = 0; nt < 4; ++nt)
          acc[mt][nt] = __builtin_amdgcn_mfma_f32_16x16x32_bf16(af[mt], bfv[nt], acc[mt][nt], 0, 0, 0);
    }
  }

  // epilogue: C row = (lane>>4)*4 + i, col = lane&15 (m89-verified layout)
#pragma unroll
  for (int mt = 0; mt < 4; ++mt) {
#pragma unroll
    for (int nt = 0; nt < 4; ++nt) {
      int row0 = m0 + wm * 64 + mt * 16 + hi * 4;
      int col = n0 + wn * 64 + nt * 16 + cl;
      float bv = bias[col];
#pragma unroll
      for (int i = 0; i < 4; ++i) {
        float v = (acc[mt][nt][i] + bv) * scale;
        int row = row0 + i;
        if (MODE == 0) {
          int b = row >> 11, s = row & 2047, h = col >> 6, d = col & 63;
          out_bf[(((size_t)(b * 8 + h)) * 2048 + s) * 64 + d] = (bf16)v;
        } else {
          out_f[(size_t)row * 512 + col] = v;
        }
      }
    }
  }
}

// ---------------- flash attention ----------------
// grid (16 qblocks, 32 bh); 4 waves x 32 q-rows; KT=64; D=64
__global__ __launch_bounds__(256) void attn_kernel(
    const bf16* __restrict__ q, const bf16* __restrict__ k,
    const bf16* __restrict__ v, bf16* __restrict__ merged)
{
  __shared__ bf16 VT[64 * 72];      // [d][key], padded stride 72 (144B, 16B-aligned, 2-way banks)
  __shared__ bf16 P[4][32 * 72];    // per-wave [qrow][key]

  const int tid = threadIdx.x, lane = tid & 63, w = tid >> 6;
  const int cl = lane & 15, hi = lane >> 4;
  const int qb = blockIdx.x, bh = blockIdx.y;
  const int b = bh >> 3, h = bh & 7;

  const bf16* Q  = q + (size_t)bh * 2048 * 64;
  const bf16* Kp = k + (size_t)bh * 2048 * 64;
  const bf16* Vp = v + (size_t)bh * 2048 * 64;

  // Q fragments in registers (Q already scaled by 0.125 at projection)
  bf16x8 qf[2][2];
#pragma unroll
  for (int rt = 0; rt < 2; ++rt)
#pragma unroll
    for (int ks = 0; ks < 2; ++ks)
      qf[rt][ks] = *(const bf16x8*)(Q + (size_t)(qb * 128 + w * 32 + rt * 16 + cl) * 64 + ks * 32 + hi * 8);

  f32x4 oacc[2][4] = {};
  float m_run[2][4], l_run[2][4];
#pragma unroll
  for (int rt = 0; rt < 2; ++rt)
#pragma unroll
    for (int i = 0; i < 4; ++i) { m_run[rt][i] = -1e30f; l_run[rt][i] = 0.f; }

  const int kp = tid & 31;           // key pair
  const int d0 = (tid >> 5) * 8;     // d block

  for (int kt0 = 0; kt0 < 2048; kt0 += 64) {
    __syncthreads();
    { // stage V^T: packed bf16x2 row writes -> conflict-free
      bf16x8 v0 = *(const bf16x8*)(Vp + (size_t)(kt0 + 2 * kp) * 64 + d0);
      bf16x8 v1 = *(const bf16x8*)(Vp + (size_t)(kt0 + 2 * kp + 1) * 64 + d0);
#pragma unroll
      for (int j = 0; j < 8; ++j) {
        bf16x2 t = { v0[j], v1[j] };
        *(bf16x2*)&VT[(d0 + j) * 72 + 2 * kp] = t;
      }
    }
    __syncthreads();

    // QK^T: K fragments direct from global (L1/L2-resident tile)
    f32x4 sc[2][4] = {};
#pragma unroll
    for (int ks = 0; ks < 2; ++ks) {
      bf16x8 kf[4];
#pragma unroll
      for (int ct = 0; ct < 4; ++ct)
        kf[ct] = *(const bf16x8*)(Kp + (size_t)(kt0 + ct * 16 + cl) * 64 + ks * 32 + hi * 8);
#pragma unroll
      for (int rt = 0; rt < 2; ++rt)
#pragma unroll
        for (int ct = 0; ct < 4; ++ct)
          sc[rt][ct] = __builtin_amdgcn_mfma_f32_16x16x32_bf16(qf[rt][ks], kf[ct], sc[rt][ct], 0, 0, 0);
    }

    // online softmax (rows live as: row = rt*16 + hi*4 + i; cols across 16-lane group)
#pragma unroll
    for (int rt = 0; rt < 2; ++rt) {
      float alpha[4];
#pragma unroll
      for (int i = 0; i < 4; ++i) {
        float t0 = fmaxf(fmaxf(sc[rt][0][i], sc[rt][1][i]), fmaxf(sc[rt][2][i], sc[rt][3][i]));
#pragma unroll
        for (int msk = 1; msk < 16; msk <<= 1) t0 = fmaxf(t0, __shfl_xor(t0, msk));
        float mn = fmaxf(m_run[rt][i], t0);
        alpha[i] = __expf(m_run[rt][i] - mn);
        m_run[rt][i] = mn;
        float rs = 0.f;
#pragma unroll
        for (int ct = 0; ct < 4; ++ct) {
          float p = __expf(sc[rt][ct][i] - mn);
          sc[rt][ct][i] = p;
          rs += p;
        }
#pragma unroll
        for (int msk = 1; msk < 16; msk <<= 1) rs += __shfl_xor(rs, msk);
        l_run[rt][i] = l_run[rt][i] * alpha[i] + rs;
      }
#pragma unroll
      for (int dt = 0; dt < 4; ++dt)
#pragma unroll
        for (int i = 0; i < 4; ++i)
          oacc[rt][dt][i] *= alpha[i];
#pragma unroll
      for (int ct = 0; ct < 4; ++ct)
#pragma unroll
        for (int i = 0; i < 4; ++i)
          P[w][(rt * 16 + hi * 4 + i) * 72 + ct * 16 + cl] = (bf16)sc[rt][ct][i];
    }

    // PV: A = P (per-wave LDS), B = V^T (block LDS)
#pragma unroll
    for (int ks = 0; ks < 2; ++ks) {
      bf16x8 pf[2], vf[4];
#pragma unroll
      for (int rt = 0; rt < 2; ++rt)
        pf[rt] = *(const bf16x8*)&P[w][(rt * 16 + cl) * 72 + ks * 32 + hi * 8];
#pragma unroll
      for (int dt = 0; dt < 4; ++dt)
        vf[dt] = *(const bf16x8*)&VT[(dt * 16 + cl) * 72 + ks * 32 + hi * 8];
#pragma unroll
      for (int rt = 0; rt < 2; ++rt)
#pragma unroll
        for (int dt = 0; dt < 4; ++dt)
          oacc[rt][dt] = __builtin_amdgcn_mfma_f32_16x16x32_bf16(pf[rt], vf[dt], oacc[rt][dt], 0, 0, 0);
    }
  }

  // epilogue: merged[b*2048+s][h*64+d] bf16
#pragma unroll
  for (int rt = 0; rt < 2; ++rt)
#pragma unroll
    for (int dt = 0; dt < 4; ++dt)
#pragma unroll
      for (int i = 0; i < 4; ++i) {
        float val = oacc[rt][dt][i] / l_run[rt][i];
        int srow = qb * 128 + w * 32 + rt * 16 + hi * 4 + i;
        int col = h * 64 + dt * 16 + cl;
        merged[((size_t)(b * 2048 + srow)) * 512 + col] = (bf16)val;
      }
}

// ---------------- launch ----------------
extern "C" void kernel_launch(void* const* d_in, const int* in_sizes, int n_in,
                              void* d_out, int out_size, void* d_ws, size_t ws_size,
                              hipStream_t stream) {
  const float* x  = (const float*)d_in[0];
  const float* Wq = (const float*)d_in[1];
  const float* bq = (const float*)d_in[2];
  const float* Wk = (const float*)d_in[3];
  const float* bk = (const float*)d_in[4];
  const float* Wv = (const float*)d_in[5];
  const float* bv = (const float*)d_in[6];
  const float* Wo = (const float*)d_in[7];
  const float* bo = (const float*)d_in[8];
  float* out = (float*)d_out;

  char* ws = (char*)d_ws;
  bf16* xb = (bf16*)(ws);                      //  8,388,608 B: x bf16 [8192][512]
  bf16* wt = (bf16*)(ws + 8388608);            //  2,097,152 B: Wt q,k,v,o [512][512] each
  bf16* qs = (bf16*)(ws + 10485760);           //  8,388,608 B: Q [B,H,S,D] (x0.125)
  bf16* kk = (bf16*)(ws + 18874368);           //  8,388,608 B: K [B,H,S,D]
  bf16* vv = (bf16*)(ws + 27262976);           //  8,388,608 B: V [B,H,S,D]
  bf16* mg = (bf16*)(ws + 35651584);           //  8,388,608 B: merged [8192][512]

  cast_x_kernel<<<4096, 256, 0, stream>>>(x, xb);
  transpose_w_kernel<<<1024, 256, 0, stream>>>(Wq, wt);
  transpose_w_kernel<<<1024, 256, 0, stream>>>(Wk, wt + 262144);
  transpose_w_kernel<<<1024, 256, 0, stream>>>(Wv, wt + 524288);
  transpose_w_kernel<<<1024, 256, 0, stream>>>(Wo, wt + 786432);

  dim3 gg(64, 4);
  gemm_tn_kernel<0><<<gg, 256, 0, stream>>>(xb, wt,          bq, qs, nullptr, 0.125f);
  gemm_tn_kernel<0><<<gg, 256, 0, stream>>>(xb, wt + 262144, bk, kk, nullptr, 1.0f);
  gemm_tn_kernel<0><<<gg, 256, 0, stream>>>(xb, wt + 524288, bv, vv, nullptr, 1.0f);

  attn_kernel<<<dim3(16, 32), 256, 0, stream>>>(qs, kk, vv, mg);

  gemm_tn_kernel<1><<<gg, 256, 0, stream>>>(mg, wt + 786432, bo, nullptr, out, 1.0f);
}

// Round 2
// 166.730 us; speedup vs baseline: 1.3812x; 1.3812x over previous
//
#include <hip/hip_runtime.h>
#include <hip/hip_bf16.h>
#include <stdint.h>

typedef __bf16 bf16;
typedef __bf16 bf16x2 __attribute__((ext_vector_type(2)));
typedef __bf16 bf16x4 __attribute__((ext_vector_type(4)));
typedef __bf16 bf16x8 __attribute__((ext_vector_type(8)));
typedef float f32x4 __attribute__((ext_vector_type(4)));
typedef float f32x16 __attribute__((ext_vector_type(16)));
typedef unsigned int u32x4 __attribute__((ext_vector_type(4)));

#define AS1 __attribute__((address_space(1)))
#define AS3 __attribute__((address_space(3)))

// B=4 S=2048 E=512 H=8 D=64; tokens M = 8192.

// ---------------- prep: cast x to bf16 ----------------
__global__ void cast_x_kernel(const float* __restrict__ x, bf16* __restrict__ xb) {
  int i = blockIdx.x * blockDim.x + threadIdx.x;  // over float4s, exactly 1M
  float4 v = reinterpret_cast<const float4*>(x)[i];
  bf16x4 o = { (bf16)v.x, (bf16)v.y, (bf16)v.z, (bf16)v.w };
  *reinterpret_cast<bf16x4*>(xb + (size_t)i * 4) = o;
}

// ---------------- prep: W[k][n] -> Wt[n][k] bf16 (LDS tile transpose, coalesced) ----
__global__ void transpose_w_kernel(const float* __restrict__ W, bf16* __restrict__ Wt) {
  __shared__ bf16 t[64][65];
  const int c = threadIdx.x & 63, r0 = threadIdx.x >> 6;
  const int bn = blockIdx.x * 64, bk = blockIdx.y * 64;
#pragma unroll
  for (int i = 0; i < 16; ++i) {
    int r = r0 * 16 + i;
    t[c][r] = (bf16)W[(size_t)(bk + r) * 512 + bn + c];
  }
  __syncthreads();
#pragma unroll
  for (int i = 0; i < 16; ++i) {
    int n = r0 * 16 + i;
    Wt[(size_t)(bn + n) * 512 + bk + c] = t[n][c];
  }
}

// ---------------- GEMM (TN): C[m][n] = sum_k A[m][k] * Bt[n][k] + bias[n] ----------------
// MODE 0: out = bf16, scatter to [B,H,S,D] split-head layout, scaled (Q: 0.125*log2e)
// MODE 1: out = f32 row-major [M][512]
template<int MODE>
__global__ __launch_bounds__(256) void gemm_tn_kernel(
    const bf16* __restrict__ A, const bf16* __restrict__ Bt,
    const float* __restrict__ bias, bf16* __restrict__ out_bf,
    float* __restrict__ out_f, float scale)
{
  __shared__ bf16 As[128 * 64];
  __shared__ bf16 Bs[128 * 64];
  const int tid = threadIdx.x;
  const int lane = tid & 63;
  const int w = tid >> 6;
  const int wm = w >> 1, wn = w & 1;           // 2x2 wave grid, 64x64 per wave
  const int m0 = blockIdx.x * 128, n0 = blockIdx.y * 128;
  const int cl = lane & 15, hi = lane >> 4;

  f32x4 acc[4][4] = {};

  const int lr = lane >> 3;
  const int cofs = ((lane & 7) << 4) ^ (lr << 4);   // pre-swizzled source byte col (T2/m173)

  const char* Abase = (const char*)A;
  const char* Bbase = (const char*)Bt;

  for (int kt = 0; kt < 512; kt += 64) {
    __syncthreads();
#pragma unroll
    for (int c = 0; c < 4; ++c) {
      int rA = m0 + w * 32 + c * 8 + lr;
      const void* srcA = Abase + ((size_t)rA * 512 + kt) * 2 + cofs;
      void* dstA = (char*)As + w * 4096 + c * 1024;
      __builtin_amdgcn_global_load_lds((const AS1 void*)srcA, (AS3 void*)dstA, 16, 0, 0);
      int rB = n0 + w * 32 + c * 8 + lr;
      const void* srcB = Bbase + ((size_t)rB * 512 + kt) * 2 + cofs;
      void* dstB = (char*)Bs + w * 4096 + c * 1024;
      __builtin_amdgcn_global_load_lds((const AS1 void*)srcB, (AS3 void*)dstB, 16, 0, 0);
    }
    __syncthreads();
#pragma unroll
    for (int ks = 0; ks < 2; ++ks) {
      bf16x8 af[4], bfv[4];
#pragma unroll
      for (int mt = 0; mt < 4; ++mt) {
        int r = wm * 64 + mt * 16 + cl;
        int cb = (ks * 64 + (hi << 4)) ^ ((r & 7) << 4);
        af[mt] = *(const bf16x8*)((const char*)As + r * 128 + cb);
      }
#pragma unroll
      for (int nt = 0; nt < 4; ++nt) {
        int r = wn * 64 + nt * 16 + cl;
        int cb = (ks * 64 + (hi << 4)) ^ ((r & 7) << 4);
        bfv[nt] = *(const bf16x8*)((const char*)Bs + r * 128 + cb);
      }
#pragma unroll
      for (int mt = 0; mt < 4; ++mt)
#pragma unroll
        for (int nt = 0; nt < 4; ++nt)
          acc[mt][nt] = __builtin_amdgcn_mfma_f32_16x16x32_bf16(af[mt], bfv[nt], acc[mt][nt], 0, 0, 0);
    }
  }

#pragma unroll
  for (int mt = 0; mt < 4; ++mt) {
#pragma unroll
    for (int nt = 0; nt < 4; ++nt) {
      int row0 = m0 + wm * 64 + mt * 16 + hi * 4;
      int col = n0 + wn * 64 + nt * 16 + cl;
      float bv = bias[col];
#pragma unroll
      for (int i = 0; i < 4; ++i) {
        float v = (acc[mt][nt][i] + bv) * scale;
        int row = row0 + i;
        if (MODE == 0) {
          int b = row >> 11, s = row & 2047, h = col >> 6, d = col & 63;
          out_bf[(((size_t)(b * 8 + h)) * 2048 + s) * 64 + d] = (bf16)v;
        } else {
          out_f[(size_t)row * 512 + col] = v;
        }
      }
    }
  }
}

// ---------------- flash attention, swapped-QK^T 32x32 (T12 structure) ----------------
// grid (16 qblocks, 32 bh); 4 waves x 32 q-rows; KVBLK=64; D=64
// Each lane owns ONE q-row (q0 + l31); scores/softmax fully lane-local + 1 shfl_xor(32).
__global__ __launch_bounds__(256) void attn_kernel(
    const bf16* __restrict__ q, const bf16* __restrict__ k,
    const bf16* __restrict__ v, bf16* __restrict__ merged)
{
  __shared__ bf16 VT[64 * 64];      // [d][key], byte-col XOR-swizzled: ^ ((d&7)<<4)
  __shared__ bf16 EP[4][32 * 72];   // per-wave epilogue transpose [q][72]

  const int tid = threadIdx.x, lane = tid & 63, w = tid >> 6;
  const int l31 = lane & 31, H = lane >> 5;
  const int qb = blockIdx.x, bh = blockIdx.y;
  const int b = bh >> 3, h = bh & 7;

  const bf16* Q  = q + (size_t)bh * 2048 * 64;
  const bf16* Kp = k + (size_t)bh * 2048 * 64;
  const bf16* Vp = v + (size_t)bh * 2048 * 64;

  const int q0 = qb * 128 + w * 32;

  // Q as B-operand frags: B[d][q], lane holds d = s*16 + H*8 + j, q = q0+l31.
  bf16x8 qf[4];
#pragma unroll
  for (int s = 0; s < 4; ++s)
    qf[s] = *(const bf16x8*)(Q + (size_t)(q0 + l31) * 64 + s * 16 + H * 8);

  f32x16 oacc[2] = {};              // O^T[d][q]: dt tile d = dt*32 + (r&3)+8*(r>>2)+4*H
  float m_run = -1e30f, l_run = 0.f;

  const int kp = tid & 31;          // key pair for V staging
  const int dblk = (tid >> 5) * 8;  // 8 d-rows per thread group

  // prologue V prefetch (T14-lite)
  bf16x8 vs0 = *(const bf16x8*)(Vp + (size_t)(2 * kp) * 64 + dblk);
  bf16x8 vs1 = *(const bf16x8*)(Vp + (size_t)(2 * kp + 1) * 64 + dblk);

  for (int kt0 = 0; kt0 < 2048; kt0 += 64) {
    __syncthreads();                // prior PV reads of VT done
    // stage V^T (swizzled), conflict-free packed bf16x2 row writes
#pragma unroll
    for (int j = 0; j < 8; ++j) {
      int d = dblk + j;
      bf16x2 t = { vs0[j], vs1[j] };
      *(bf16x2*)((char*)VT + d * 128 + ((4 * kp) ^ ((d & 7) << 4))) = t;
    }
    // issue next tile's V loads now; they fly over QK^T+softmax+PV
    if (kt0 + 64 < 2048) {
      vs0 = *(const bf16x8*)(Vp + (size_t)(kt0 + 64 + 2 * kp) * 64 + dblk);
      vs1 = *(const bf16x8*)(Vp + (size_t)(kt0 + 64 + 2 * kp + 1) * 64 + dblk);
    }
    __syncthreads();                // VT ready

    // QK^T swapped: S^T[key][q] = K · Q^T ; K-frags direct from global (L2-resident)
    f32x16 sc[2] = {};
#pragma unroll
    for (int ct = 0; ct < 2; ++ct) {
      bf16x8 kf[4];
#pragma unroll
      for (int s = 0; s < 4; ++s)
        kf[s] = *(const bf16x8*)(Kp + (size_t)(kt0 + ct * 32 + l31) * 64 + s * 16 + H * 8);
#pragma unroll
      for (int s = 0; s < 4; ++s)
        sc[ct] = __builtin_amdgcn_mfma_f32_32x32x16_bf16(kf[s], qf[s], sc[ct], 0, 0, 0);
    }

    // ---- lane-local online softmax (q-row = q0+l31; other 32 keys live in lane^32) ----
    float mx[16];
#pragma unroll
    for (int r = 0; r < 16; ++r) mx[r] = fmaxf(sc[0][r], sc[1][r]);
#pragma unroll
    for (int s2 = 8; s2 > 0; s2 >>= 1)
#pragma unroll
      for (int r = 0; r < s2; ++r) mx[r] = fmaxf(mx[r], mx[r + s2]);
    float pmax = fmaxf(mx[0], __shfl_xor(mx[0], 32));

    float mn = fmaxf(m_run, pmax);
    float alpha = exp2f(m_run - mn);
    m_run = mn;
#pragma unroll
    for (int ct = 0; ct < 2; ++ct)
#pragma unroll
      for (int r = 0; r < 16; ++r) sc[ct][r] = exp2f(sc[ct][r] - mn);

    float sm[16];
#pragma unroll
    for (int r = 0; r < 16; ++r) sm[r] = sc[0][r] + sc[1][r];
#pragma unroll
    for (int s2 = 8; s2 > 0; s2 >>= 1)
#pragma unroll
      for (int r = 0; r < s2; ++r) sm[r] += sm[r + s2];
    float rs = sm[0] + __shfl_xor(sm[0], 32);
    l_run = l_run * alpha + rs;
#pragma unroll
    for (int dt = 0; dt < 2; ++dt)
#pragma unroll
      for (int r = 0; r < 16; ++r) oacc[dt][r] *= alpha;

    // ---- in-register P -> bf16 B-frags (pack + shfl_xor(32) + select), then PV ----
#pragma unroll
    for (int ks = 0; ks < 4; ++ks) {
      const int ct = ks >> 1;
      const int g0 = 8 * (ks & 1);
      bf16x2 pa0 = { (bf16)sc[ct][g0 + 0], (bf16)sc[ct][g0 + 1] };
      bf16x2 pa1 = { (bf16)sc[ct][g0 + 2], (bf16)sc[ct][g0 + 3] };
      bf16x2 pb0 = { (bf16)sc[ct][g0 + 4], (bf16)sc[ct][g0 + 5] };
      bf16x2 pb1 = { (bf16)sc[ct][g0 + 6], (bf16)sc[ct][g0 + 7] };
      unsigned a0 = __builtin_bit_cast(unsigned, pa0);
      unsigned a1 = __builtin_bit_cast(unsigned, pa1);
      unsigned b0 = __builtin_bit_cast(unsigned, pb0);
      unsigned b1 = __builtin_bit_cast(unsigned, pb1);
      unsigned oa0 = (unsigned)__shfl_xor((int)a0, 32);
      unsigned oa1 = (unsigned)__shfl_xor((int)a1, 32);
      unsigned ob0 = (unsigned)__shfl_xor((int)b0, 32);
      unsigned ob1 = (unsigned)__shfl_xor((int)b1, 32);
      u32x4 pw = { H ? ob0 : a0, H ? ob1 : a1, H ? b0 : oa0, H ? b1 : oa1 };
      bf16x8 pf = __builtin_bit_cast(bf16x8, pw);
#pragma unroll
      for (int dt = 0; dt < 2; ++dt) {
        int d = dt * 32 + l31;
        bf16x8 vf = *(const bf16x8*)((const char*)VT + d * 128 + ((ks * 32 + H * 16) ^ ((d & 7) << 4)));
        oacc[dt] = __builtin_amdgcn_mfma_f32_32x32x16_bf16(vf, pf, oacc[dt], 0, 0, 0);
      }
    }
  }

  // ---- epilogue: O = (O^T)/l, transpose per-wave via LDS, coalesced 16B stores ----
  float inv_l = 1.0f / l_run;
#pragma unroll
  for (int dt = 0; dt < 2; ++dt)
#pragma unroll
    for (int r = 0; r < 16; ++r) {
      int d = dt * 32 + (r & 3) + 8 * (r >> 2) + 4 * H;
      EP[w][l31 * 72 + d] = (bf16)(oacc[dt][r] * inv_l);
    }
  __builtin_amdgcn_s_waitcnt(0);  // lgkm drain before same-wave readback (compiler also guards)
#pragma unroll
  for (int g = 0; g < 4; ++g) {
    int qr = g * 8 + (lane >> 3);
    bf16x8 row = *(const bf16x8*)&EP[w][qr * 72 + (lane & 7) * 8];
    *(bf16x8*)(merged + (size_t)(b * 2048 + q0 + qr) * 512 + h * 64 + (lane & 7) * 8) = row;
  }
}

// ---------------- launch ----------------
extern "C" void kernel_launch(void* const* d_in, const int* in_sizes, int n_in,
                              void* d_out, int out_size, void* d_ws, size_t ws_size,
                              hipStream_t stream) {
  const float* x  = (const float*)d_in[0];
  const float* Wq = (const float*)d_in[1];
  const float* bq = (const float*)d_in[2];
  const float* Wk = (const float*)d_in[3];
  const float* bk = (const float*)d_in[4];
  const float* Wv = (const float*)d_in[5];
  const float* bv = (const float*)d_in[6];
  const float* Wo = (const float*)d_in[7];
  const float* bo = (const float*)d_in[8];
  float* out = (float*)d_out;

  char* ws = (char*)d_ws;
  bf16* xb = (bf16*)(ws);                      //  8,388,608 B: x bf16 [8192][512]
  bf16* wt = (bf16*)(ws + 8388608);            //  2,097,152 B: Wt q,k,v,o [512][512] each
  bf16* qs = (bf16*)(ws + 10485760);           //  8,388,608 B: Q [B,H,S,D] (x 0.125*log2e)
  bf16* kk = (bf16*)(ws + 18874368);           //  8,388,608 B: K [B,H,S,D]
  bf16* vv = (bf16*)(ws + 27262976);           //  8,388,608 B: V [B,H,S,D]
  bf16* mg = (bf16*)(ws + 35651584);           //  8,388,608 B: merged [8192][512]

  cast_x_kernel<<<4096, 256, 0, stream>>>(x, xb);
  dim3 tg(8, 8);
  transpose_w_kernel<<<tg, 256, 0, stream>>>(Wq, wt);
  transpose_w_kernel<<<tg, 256, 0, stream>>>(Wk, wt + 262144);
  transpose_w_kernel<<<tg, 256, 0, stream>>>(Wv, wt + 524288);
  transpose_w_kernel<<<tg, 256, 0, stream>>>(Wo, wt + 786432);

  const float qscale = 0.125f * 1.44269504088896f;  // fold log2(e): exp -> exp2 in softmax
  dim3 gg(64, 4);
  gemm_tn_kernel<0><<<gg, 256, 0, stream>>>(xb, wt,          bq, qs, nullptr, qscale);
  gemm_tn_kernel<0><<<gg, 256, 0, stream>>>(xb, wt + 262144, bk, kk, nullptr, 1.0f);
  gemm_tn_kernel<0><<<gg, 256, 0, stream>>>(xb, wt + 524288, bv, vv, nullptr, 1.0f);

  attn_kernel<<<dim3(16, 32), 256, 0, stream>>>(qs, kk, vv, mg);

  gemm_tn_kernel<1><<<gg, 256, 0, stream>>>(mg, wt + 786432, bo, nullptr, out, 1.0f);
}